// Round 2
// baseline (635.325 us; speedup 1.0000x reference)
//
#include <hip/hip_runtime.h>
#include <math.h>

#define NN 8192
#define NF 128

// ws layout (float indices):
// dinv   [0, 8192)
// c0     [8192, 16384)
// xw     [16384, 98304)        8192*10   (x@W1, UNSCALED)
// yraw   [98304, 180224)       8192*10   (adj@xw, raw)
// h      [180224, 262144)      8192*10
// accum  [262144, 262154)      10 floats (zeroed by memset)
// Zcount int at 262154         (zeroed by same memset)
// Zlist  ints [262155, +8192)
// slab   [270592, 270592+512*8192)   16 MiB colsum partials
// total ~17.1 MB

// ---------------------------------------------------------------------------
// kS0: xw[j,k] = x[j,:] @ W1[:,k]   (UNSCALED — dinv not known yet)
// ---------------------------------------------------------------------------
__global__ __launch_bounds__(256) void kS0(const float* __restrict__ x,
                                           const float* __restrict__ W1,
                                           float* __restrict__ xw) {
    __shared__ float sW[NF * 10];
    for (int i = threadIdx.x; i < NF * 10; i += 256) sW[i] = W1[i];
    __syncthreads();
    int tid = blockIdx.x * 256 + threadIdx.x;   // = j*10 + k, 81920 total
    int j = tid / 10, k = tid % 10;
    const float4* xr = (const float4*)(x + (size_t)j * NF);
    float s = 0.f;
#pragma unroll
    for (int f4 = 0; f4 < 32; f4++) {
        float4 a = xr[f4];
        s += a.x * sW[(f4 * 4 + 0) * 10 + k] + a.y * sW[(f4 * 4 + 1) * 10 + k]
           + a.z * sW[(f4 * 4 + 2) * 10 + k] + a.w * sW[(f4 * 4 + 3) * 10 + k];
    }
    xw[tid] = s;
}

// ---------------------------------------------------------------------------
// kMain: SINGLE pass over adj. 512 blocks x 256 threads; block owns 16 rows,
// processed as 4 tiles of 4 rows. Thread t owns float4-columns {it*256+t},
// so colsum partials live in 8 float4 registers across all rows, flushed
// once per block to slab (coalesced stores, no atomics).
// Per tile: yraw (raw adj@xw matvec) + per-row degree count.
// ---------------------------------------------------------------------------
__global__ __launch_bounds__(256) void kMain(const float* __restrict__ adj,
                                             const float* __restrict__ xw,
                                             float* __restrict__ dinv,
                                             float* __restrict__ yraw,
                                             float* __restrict__ slab,
                                             int* __restrict__ Zcount,
                                             int* __restrict__ Zlist) {
    const int t = threadIdx.x;
    const int lane = t & 63, wid = t >> 6;
    const int rowBase = blockIdx.x * 16;
    float* myslab = slab + (size_t)blockIdx.x * NN;
    __shared__ float sh[4][44];

    float4 csum[8];
#pragma unroll
    for (int q = 0; q < 8; q++) csum[q] = make_float4(0.f, 0.f, 0.f, 0.f);

    for (int tile = 0; tile < 4; tile++) {
        const int i0 = rowBase + tile * 4;
        const float4* r0 = (const float4*)(adj + (size_t)(i0 + 0) * NN);
        const float4* r1 = (const float4*)(adj + (size_t)(i0 + 1) * NN);
        const float4* r2 = (const float4*)(adj + (size_t)(i0 + 2) * NN);
        const float4* r3 = (const float4*)(adj + (size_t)(i0 + 3) * NN);
        float acc[4][10];
        int cnt[4] = {0, 0, 0, 0};
#pragma unroll
        for (int r = 0; r < 4; r++)
#pragma unroll
            for (int k = 0; k < 10; k++) acc[r][k] = 0.f;

#pragma unroll
        for (int it = 0; it < 8; it++) {
            const int c4 = it * 256 + t;
            float4 a0 = r0[c4], a1 = r1[c4], a2 = r2[c4], a3 = r3[c4];
            const float4* xp = (const float4*)(xw + (size_t)c4 * 40);
            float sv[40];
#pragma unroll
            for (int q = 0; q < 10; q++) {
                float4 v = xp[q];
                sv[q * 4 + 0] = v.x; sv[q * 4 + 1] = v.y;
                sv[q * 4 + 2] = v.z; sv[q * 4 + 3] = v.w;
            }
#pragma unroll
            for (int k = 0; k < 10; k++) {
                acc[0][k] += a0.x * sv[k] + a0.y * sv[10 + k] + a0.z * sv[20 + k] + a0.w * sv[30 + k];
                acc[1][k] += a1.x * sv[k] + a1.y * sv[10 + k] + a1.z * sv[20 + k] + a1.w * sv[30 + k];
                acc[2][k] += a2.x * sv[k] + a2.y * sv[10 + k] + a2.z * sv[20 + k] + a2.w * sv[30 + k];
                acc[3][k] += a3.x * sv[k] + a3.y * sv[10 + k] + a3.z * sv[20 + k] + a3.w * sv[30 + k];
            }
            csum[it].x += a0.x + a1.x + a2.x + a3.x;
            csum[it].y += a0.y + a1.y + a2.y + a3.y;
            csum[it].z += a0.z + a1.z + a2.z + a3.z;
            csum[it].w += a0.w + a1.w + a2.w + a3.w;
            cnt[0] += (a0.x > 0.f) + (a0.y > 0.f) + (a0.z > 0.f) + (a0.w > 0.f);
            cnt[1] += (a1.x > 0.f) + (a1.y > 0.f) + (a1.z > 0.f) + (a1.w > 0.f);
            cnt[2] += (a2.x > 0.f) + (a2.y > 0.f) + (a2.z > 0.f) + (a2.w > 0.f);
            cnt[3] += (a3.x > 0.f) + (a3.y > 0.f) + (a3.z > 0.f) + (a3.w > 0.f);
        }
        // wave reduce 40 floats + 4 ints
#pragma unroll
        for (int r = 0; r < 4; r++) {
#pragma unroll
            for (int k = 0; k < 10; k++)
#pragma unroll
                for (int off = 32; off > 0; off >>= 1)
                    acc[r][k] += __shfl_xor(acc[r][k], off, 64);
#pragma unroll
            for (int off = 32; off > 0; off >>= 1)
                cnt[r] += __shfl_xor(cnt[r], off, 64);
        }
        if (lane == 0) {
#pragma unroll
            for (int q = 0; q < 40; q++) sh[wid][q] = acc[q / 10][q % 10];
#pragma unroll
            for (int r = 0; r < 4; r++) sh[wid][40 + r] = (float)cnt[r];
        }
        __syncthreads();
        if (t < 44) {
            float v = sh[0][t] + sh[1][t] + sh[2][t] + sh[3][t];
            if (t < 40) {
                yraw[(i0 + t / 10) * 10 + (t % 10)] = v;
            } else {
                int r = t - 40;
                int d = (int)v;
                dinv[i0 + r] = rsqrtf((float)d);
                if (d != NN) { int p = atomicAdd(Zcount, 1); Zlist[p] = i0 + r; }
            }
        }
        __syncthreads();
    }
    // flush colsum partials — coalesced float4 stores, no atomics
#pragma unroll
    for (int it = 0; it < 8; it++)
        ((float4*)myslab)[it * 256 + t] = csum[it];
}

// ---------------------------------------------------------------------------
// kRedC: colsum_j = sum_b slab[b][j];
// c_j = dinv0*colsum_j + sum_{i in Z} (dinv_i - dinv0)*adj[i][j]   (exact)
// ---------------------------------------------------------------------------
__global__ __launch_bounds__(256) void kRedC(const float* __restrict__ adj,
                                             const float* __restrict__ dinv,
                                             const float* __restrict__ slab,
                                             float* __restrict__ c0,
                                             const int* __restrict__ Zcount,
                                             const int* __restrict__ Zlist) {
    int j = blockIdx.x * 256 + threadIdx.x;
    float s = 0.f;
    for (int b = 0; b < 512; b++) s += slab[(size_t)b * NN + j];
    const float dinv0 = rsqrtf((float)NN);
    float v = s * dinv0;
    int zc = *Zcount;
    for (int p = 0; p < zc; p++) {
        int zi = Zlist[p];
        v += (dinv[zi] - dinv0) * adj[(size_t)zi * NN + j];
    }
    c0[j] = v;
}

// ---------------------------------------------------------------------------
// kFix: h[i,k] = relu( di*( dinv0*yraw[i,k] + corr[i,k] + di*xw[i,k] ) + b1[k] )
// corr[i,k] = sum_{j in Z} (dinv_j - dinv0)*adj[i][j]*xw[j,k]
// ---------------------------------------------------------------------------
__global__ __launch_bounds__(128) void kFix(const float* __restrict__ adj,
                                            const float* __restrict__ xw,
                                            const float* __restrict__ yraw,
                                            const float* __restrict__ dinv,
                                            const float* __restrict__ b1,
                                            float* __restrict__ h,
                                            const int* __restrict__ Zcount,
                                            const int* __restrict__ Zlist) {
    int i = blockIdx.x * 128 + threadIdx.x;
    const float dinv0 = rsqrtf((float)NN);
    float corr[10];
#pragma unroll
    for (int k = 0; k < 10; k++) corr[k] = 0.f;
    int zc = *Zcount;
    for (int p = 0; p < zc; p++) {
        int zj = Zlist[p];
        float w = (dinv[zj] - dinv0) * adj[(size_t)i * NN + zj];
#pragma unroll
        for (int k = 0; k < 10; k++) corr[k] += w * xw[zj * 10 + k];
    }
    float di = dinv[i];
#pragma unroll
    for (int k = 0; k < 10; k++) {
        float v = di * (dinv0 * yraw[i * 10 + k] + corr[k] + di * xw[i * 10 + k]) + b1[k];
        h[i * 10 + k] = fmaxf(v, 0.f);
    }
}

// ---------------------------------------------------------------------------
// kF1: s2[j,k] = (h[j,:]@W2[:,k])*dinv_j (k<5)
// accum[k]   += c_j   * s2[j,k];  accum[5+k] += dinv_j * s2[j,k]
// ---------------------------------------------------------------------------
__global__ __launch_bounds__(256) void kF1(const float* __restrict__ h,
                                           const float* __restrict__ dinv,
                                           const float* __restrict__ c0,
                                           const float* __restrict__ W2,
                                           float* __restrict__ accum) {
    int j = blockIdx.x * 256 + threadIdx.x;
    float hv[10];
#pragma unroll
    for (int m = 0; m < 10; m++) hv[m] = h[j * 10 + m];
    float dj = dinv[j], cj = c0[j];
    float p[10];
#pragma unroll
    for (int k = 0; k < 5; k++) {
        float s = 0.f;
#pragma unroll
        for (int m = 0; m < 10; m++) s += hv[m] * W2[m * 5 + k];
        s *= dj;
        p[k] = cj * s;
        p[5 + k] = dj * s;
    }
#pragma unroll
    for (int q = 0; q < 10; q++) {
        float v = p[q];
#pragma unroll
        for (int off = 32; off > 0; off >>= 1) v += __shfl_xor(v, off, 64);
        if ((threadIdx.x & 63) == 0) atomicAdd(&accum[q], v);
    }
}

// ---------------------------------------------------------------------------
// kF2: z = relu((S1+S2)/N + b2); z2 = relu(z@fc1_W+fc1_b); y = sigmoid(...)
// out = [z(5), y(2)]
// ---------------------------------------------------------------------------
__global__ void kF2(const float* __restrict__ accum, const float* __restrict__ b2,
                    const float* __restrict__ fc1W, const float* __restrict__ fc1b,
                    const float* __restrict__ fcW, const float* __restrict__ fcb,
                    float* __restrict__ out) {
    if (threadIdx.x == 0 && blockIdx.x == 0) {
        float z[5];
        for (int k = 0; k < 5; k++) {
            float v = (accum[k] + accum[5 + k]) * (1.f / (float)NN) + b2[k];
            z[k] = fmaxf(v, 0.f);
            out[k] = z[k];
        }
        float z2[5];
        for (int m = 0; m < 5; m++) {
            float v = fc1b[m];
            for (int k = 0; k < 5; k++) v += z[k] * fc1W[k * 5 + m];
            z2[m] = fmaxf(v, 0.f);
        }
        for (int n = 0; n < 2; n++) {
            float v = fcb[n];
            for (int m = 0; m < 5; m++) v += z2[m] * fcW[m * 2 + n];
            out[5 + n] = 1.f / (1.f + expf(-v));
        }
    }
}

extern "C" void kernel_launch(void* const* d_in, const int* in_sizes, int n_in,
                              void* d_out, int out_size, void* d_ws, size_t ws_size,
                              hipStream_t stream) {
    const float* x    = (const float*)d_in[0];
    const float* adj  = (const float*)d_in[1];
    const float* W1   = (const float*)d_in[2];
    const float* b1   = (const float*)d_in[3];
    const float* W2   = (const float*)d_in[4];
    const float* b2   = (const float*)d_in[5];
    const float* fc1W = (const float*)d_in[6];
    const float* fc1b = (const float*)d_in[7];
    const float* fcW  = (const float*)d_in[8];
    const float* fcb  = (const float*)d_in[9];
    (void)in_sizes; (void)n_in; (void)out_size; (void)ws_size;

    float* ws     = (float*)d_ws;
    float* dinv   = ws;
    float* c0     = ws + 8192;
    float* xw     = ws + 16384;
    float* yraw   = ws + 98304;
    float* h      = ws + 180224;
    float* accum  = ws + 262144;
    int*   Zcount = (int*)(ws + 262154);
    int*   Zlist  = (int*)(ws + 262155);
    float* slab   = ws + 270592;
    float* out    = (float*)d_out;

    // zero accum[10] + Zcount (contiguous 44+4 bytes)
    hipMemsetAsync(accum, 0, 48, stream);

    kS0  <<<320, 256, 0, stream>>>(x, W1, xw);
    kMain<<<512, 256, 0, stream>>>(adj, xw, dinv, yraw, slab, Zcount, Zlist);
    kRedC<<<32,  256, 0, stream>>>(adj, dinv, slab, c0, Zcount, Zlist);
    kFix <<<64,  128, 0, stream>>>(adj, xw, yraw, dinv, b1, h, Zcount, Zlist);
    kF1  <<<32,  256, 0, stream>>>(h, dinv, c0, W2, accum);
    kF2  <<<1,   64,  0, stream>>>(accum, b2, fc1W, fc1b, fcW, fcb, out);
}

// Round 3
// 585.395 us; speedup vs baseline: 1.0853x; 1.0853x over previous
//
#include <hip/hip_runtime.h>
#include <math.h>

#define NN 8192
#define NF 128

// ws layout (float indices):
// c0     [0, 8192)        zeroed (atomic colsum accum -> finalized c)
// accum  [8192, 8202)     zeroed
// Zcount int at 8202      zeroed   (single memset covers [0, 8203))
// Zlist  ints [8203, +8192)
// dinv   [16395, 24587)
// xw     [24587, 106507)      8192*10 (x@W1, UNSCALED)
// yraw   [106507, 188427)     8192*10 (adj@xw raw)
// h      [188427, 270347)     8192*10
// slab   [270592, 270592+1024*8192)  32 MiB colsum partials
// total ~34 MB

// ---------------------------------------------------------------------------
// kS0: xw[j,k] = x[j,:] @ W1[:,k]   (UNSCALED)
// ---------------------------------------------------------------------------
__global__ __launch_bounds__(256) void kS0(const float* __restrict__ x,
                                           const float* __restrict__ W1,
                                           float* __restrict__ xw) {
    __shared__ float sW[NF * 10];
    for (int i = threadIdx.x; i < NF * 10; i += 256) sW[i] = W1[i];
    __syncthreads();
    int tid = blockIdx.x * 256 + threadIdx.x;   // = j*10 + k
    int j = tid / 10, k = tid % 10;
    const float4* xr = (const float4*)(x + (size_t)j * NF);
    float s = 0.f;
#pragma unroll
    for (int f4 = 0; f4 < 32; f4++) {
        float4 a = xr[f4];
        s += a.x * sW[(f4 * 4 + 0) * 10 + k] + a.y * sW[(f4 * 4 + 1) * 10 + k]
           + a.z * sW[(f4 * 4 + 2) * 10 + k] + a.w * sW[(f4 * 4 + 3) * 10 + k];
    }
    xw[tid] = s;
}

// ---------------------------------------------------------------------------
// kMain: single pass over adj. 1024 blocks x 256 threads; block owns 8 rows
// (2 tiles x 4 rows). Thread t owns float4-column c4 = it*256+t per it, so
// per-thread colsum partials live in csum[8] float4 regs across both tiles,
// flushed once to slab (coalesced, no atomics). Per tile: raw adj@xw matvec
// into acc[4][10] + per-row degree counts. xw float4s consumed immediately
// (no 40-float staging array); it-loop unroll bounded to 2 to avoid the
// R2 spill (VGPR=256, 160MB scratch writes).
// ---------------------------------------------------------------------------
__global__ __launch_bounds__(256, 3) void kMain(const float* __restrict__ adj,
                                                const float* __restrict__ xw,
                                                float* __restrict__ dinv,
                                                float* __restrict__ yraw,
                                                float* __restrict__ slab,
                                                int* __restrict__ Zcount,
                                                int* __restrict__ Zlist) {
    const int t = threadIdx.x;
    const int lane = t & 63, wid = t >> 6;
    const int rowBase = blockIdx.x * 8;
    float* myslab = slab + (size_t)blockIdx.x * NN;
    __shared__ float sh[4][44];

    float4 csum[8];
#pragma unroll
    for (int q = 0; q < 8; q++) csum[q] = make_float4(0.f, 0.f, 0.f, 0.f);

    for (int tile = 0; tile < 2; tile++) {
        const int i0 = rowBase + tile * 4;
        const float4* r0 = (const float4*)(adj + (size_t)(i0 + 0) * NN);
        const float4* r1 = (const float4*)(adj + (size_t)(i0 + 1) * NN);
        const float4* r2 = (const float4*)(adj + (size_t)(i0 + 2) * NN);
        const float4* r3 = (const float4*)(adj + (size_t)(i0 + 3) * NN);
        float acc[4][10];
        int cnt[4] = {0, 0, 0, 0};
#pragma unroll
        for (int r = 0; r < 4; r++)
#pragma unroll
            for (int k = 0; k < 10; k++) acc[r][k] = 0.f;

#pragma unroll 2
        for (int it = 0; it < 8; it++) {
            const int c4 = it * 256 + t;
            float4 a0 = r0[c4], a1 = r1[c4], a2 = r2[c4], a3 = r3[c4];
            const float4* xp = (const float4*)(xw + (size_t)c4 * 40);
            // consume each xw float4 immediately: flat index m = 4q+e,
            // jj = m/10 selects a-component, k = m%10 selects acc column
#pragma unroll
            for (int q = 0; q < 10; q++) {
                float4 v = xp[q];
#pragma unroll
                for (int e = 0; e < 4; e++) {
                    const int m = 4 * q + e;
                    const int jj = m / 10, k = m % 10;
                    const float vv = (e == 0) ? v.x : (e == 1) ? v.y : (e == 2) ? v.z : v.w;
                    const float b0 = (jj == 0) ? a0.x : (jj == 1) ? a0.y : (jj == 2) ? a0.z : a0.w;
                    const float b1 = (jj == 0) ? a1.x : (jj == 1) ? a1.y : (jj == 2) ? a1.z : a1.w;
                    const float b2 = (jj == 0) ? a2.x : (jj == 1) ? a2.y : (jj == 2) ? a2.z : a2.w;
                    const float b3 = (jj == 0) ? a3.x : (jj == 1) ? a3.y : (jj == 2) ? a3.z : a3.w;
                    acc[0][k] += b0 * vv;
                    acc[1][k] += b1 * vv;
                    acc[2][k] += b2 * vv;
                    acc[3][k] += b3 * vv;
                }
            }
            csum[it].x += a0.x + a1.x + a2.x + a3.x;
            csum[it].y += a0.y + a1.y + a2.y + a3.y;
            csum[it].z += a0.z + a1.z + a2.z + a3.z;
            csum[it].w += a0.w + a1.w + a2.w + a3.w;
            cnt[0] += (a0.x > 0.f) + (a0.y > 0.f) + (a0.z > 0.f) + (a0.w > 0.f);
            cnt[1] += (a1.x > 0.f) + (a1.y > 0.f) + (a1.z > 0.f) + (a1.w > 0.f);
            cnt[2] += (a2.x > 0.f) + (a2.y > 0.f) + (a2.z > 0.f) + (a2.w > 0.f);
            cnt[3] += (a3.x > 0.f) + (a3.y > 0.f) + (a3.z > 0.f) + (a3.w > 0.f);
        }
        // wave reduce 40 floats + 4 ints
#pragma unroll
        for (int r = 0; r < 4; r++) {
#pragma unroll
            for (int k = 0; k < 10; k++)
#pragma unroll
                for (int off = 32; off > 0; off >>= 1)
                    acc[r][k] += __shfl_xor(acc[r][k], off, 64);
#pragma unroll
            for (int off = 32; off > 0; off >>= 1)
                cnt[r] += __shfl_xor(cnt[r], off, 64);
        }
        if (lane == 0) {
#pragma unroll
            for (int q = 0; q < 40; q++) sh[wid][q] = acc[q / 10][q % 10];
#pragma unroll
            for (int r = 0; r < 4; r++) sh[wid][40 + r] = (float)cnt[r];
        }
        __syncthreads();
        if (t < 44) {
            float v = sh[0][t] + sh[1][t] + sh[2][t] + sh[3][t];
            if (t < 40) {
                yraw[(i0 + t / 10) * 10 + (t % 10)] = v;
            } else {
                int r = t - 40;
                int d = (int)v;
                dinv[i0 + r] = rsqrtf((float)d);
                if (d != NN) { int p = atomicAdd(Zcount, 1); Zlist[p] = i0 + r; }
            }
        }
        __syncthreads();
    }
    // flush colsum partials — coalesced float4 stores, no atomics
#pragma unroll
    for (int it = 0; it < 8; it++)
        ((float4*)myslab)[it * 256 + t] = csum[it];
}

// ---------------------------------------------------------------------------
// kRedC1: c0[j] += dinv0 * sum_{b in bseg} slab[b][j]   (c0 pre-zeroed)
// grid 256 = 32 j-segments x 8 b-segments; 8 atomic adds per j total.
// ---------------------------------------------------------------------------
__global__ __launch_bounds__(256) void kRedC1(const float* __restrict__ slab,
                                              float* __restrict__ c0) {
    int jseg = blockIdx.x & 31, bseg = blockIdx.x >> 5;
    int j = jseg * 256 + threadIdx.x;
    float s = 0.f;
    for (int b = bseg * 128; b < bseg * 128 + 128; b++)
        s += slab[(size_t)b * NN + j];
    const float dinv0 = rsqrtf((float)NN);
    atomicAdd(&c0[j], s * dinv0);
}

// ---------------------------------------------------------------------------
// kRedC2: c0[j] += sum_{i in Z} (dinv_i - dinv0) * adj[i][j]   (exact)
// ---------------------------------------------------------------------------
__global__ __launch_bounds__(256) void kRedC2(const float* __restrict__ adj,
                                              const float* __restrict__ dinv,
                                              float* __restrict__ c0,
                                              const int* __restrict__ Zcount,
                                              const int* __restrict__ Zlist) {
    int j = blockIdx.x * 256 + threadIdx.x;
    const float dinv0 = rsqrtf((float)NN);
    float v = 0.f;
    int zc = *Zcount;
    for (int p = 0; p < zc; p++) {
        int zi = Zlist[p];
        v += (dinv[zi] - dinv0) * adj[(size_t)zi * NN + j];
    }
    c0[j] += v;
}

// ---------------------------------------------------------------------------
// kFix: h[i,k] = relu( di*( dinv0*yraw[i,k] + corr[i,k] + di*xw[i,k] ) + b1[k] )
// corr[i,k] = sum_{j in Z} (dinv_j - dinv0)*adj[i][j]*xw[j,k]
// ---------------------------------------------------------------------------
__global__ __launch_bounds__(128) void kFix(const float* __restrict__ adj,
                                            const float* __restrict__ xw,
                                            const float* __restrict__ yraw,
                                            const float* __restrict__ dinv,
                                            const float* __restrict__ b1,
                                            float* __restrict__ h,
                                            const int* __restrict__ Zcount,
                                            const int* __restrict__ Zlist) {
    int i = blockIdx.x * 128 + threadIdx.x;
    const float dinv0 = rsqrtf((float)NN);
    float corr[10];
#pragma unroll
    for (int k = 0; k < 10; k++) corr[k] = 0.f;
    int zc = *Zcount;
    for (int p = 0; p < zc; p++) {
        int zj = Zlist[p];
        float w = (dinv[zj] - dinv0) * adj[(size_t)i * NN + zj];
#pragma unroll
        for (int k = 0; k < 10; k++) corr[k] += w * xw[zj * 10 + k];
    }
    float di = dinv[i];
#pragma unroll
    for (int k = 0; k < 10; k++) {
        float v = di * (dinv0 * yraw[i * 10 + k] + corr[k] + di * xw[i * 10 + k]) + b1[k];
        h[i * 10 + k] = fmaxf(v, 0.f);
    }
}

// ---------------------------------------------------------------------------
// kF1: s2[j,k] = (h[j,:]@W2[:,k])*dinv_j (k<5)
// accum[k] += c_j * s2[j,k];  accum[5+k] += dinv_j * s2[j,k]
// ---------------------------------------------------------------------------
__global__ __launch_bounds__(256) void kF1(const float* __restrict__ h,
                                           const float* __restrict__ dinv,
                                           const float* __restrict__ c0,
                                           const float* __restrict__ W2,
                                           float* __restrict__ accum) {
    int j = blockIdx.x * 256 + threadIdx.x;
    float hv[10];
#pragma unroll
    for (int m = 0; m < 10; m++) hv[m] = h[j * 10 + m];
    float dj = dinv[j], cj = c0[j];
    float p[10];
#pragma unroll
    for (int k = 0; k < 5; k++) {
        float s = 0.f;
#pragma unroll
        for (int m = 0; m < 10; m++) s += hv[m] * W2[m * 5 + k];
        s *= dj;
        p[k] = cj * s;
        p[5 + k] = dj * s;
    }
#pragma unroll
    for (int q = 0; q < 10; q++) {
        float v = p[q];
#pragma unroll
        for (int off = 32; off > 0; off >>= 1) v += __shfl_xor(v, off, 64);
        if ((threadIdx.x & 63) == 0) atomicAdd(&accum[q], v);
    }
}

// ---------------------------------------------------------------------------
// kF2: z = relu((S1+S2)/N + b2); z2 = relu(z@fc1_W+fc1_b); y = sigmoid(...)
// out = [z(5), y(2)]
// ---------------------------------------------------------------------------
__global__ void kF2(const float* __restrict__ accum, const float* __restrict__ b2,
                    const float* __restrict__ fc1W, const float* __restrict__ fc1b,
                    const float* __restrict__ fcW, const float* __restrict__ fcb,
                    float* __restrict__ out) {
    if (threadIdx.x == 0 && blockIdx.x == 0) {
        float z[5];
        for (int k = 0; k < 5; k++) {
            float v = (accum[k] + accum[5 + k]) * (1.f / (float)NN) + b2[k];
            z[k] = fmaxf(v, 0.f);
            out[k] = z[k];
        }
        float z2[5];
        for (int m = 0; m < 5; m++) {
            float v = fc1b[m];
            for (int k = 0; k < 5; k++) v += z[k] * fc1W[k * 5 + m];
            z2[m] = fmaxf(v, 0.f);
        }
        for (int n = 0; n < 2; n++) {
            float v = fcb[n];
            for (int m = 0; m < 5; m++) v += z2[m] * fcW[m * 2 + n];
            out[5 + n] = 1.f / (1.f + expf(-v));
        }
    }
}

extern "C" void kernel_launch(void* const* d_in, const int* in_sizes, int n_in,
                              void* d_out, int out_size, void* d_ws, size_t ws_size,
                              hipStream_t stream) {
    const float* x    = (const float*)d_in[0];
    const float* adj  = (const float*)d_in[1];
    const float* W1   = (const float*)d_in[2];
    const float* b1   = (const float*)d_in[3];
    const float* W2   = (const float*)d_in[4];
    const float* b2   = (const float*)d_in[5];
    const float* fc1W = (const float*)d_in[6];
    const float* fc1b = (const float*)d_in[7];
    const float* fcW  = (const float*)d_in[8];
    const float* fcb  = (const float*)d_in[9];
    (void)in_sizes; (void)n_in; (void)out_size; (void)ws_size;

    float* ws     = (float*)d_ws;
    float* c0     = ws;                  // [0, 8192)
    float* accum  = ws + 8192;           // [8192, 8202)
    int*   Zcount = (int*)(ws + 8202);
    int*   Zlist  = (int*)(ws + 8203);
    float* dinv   = ws + 16395;
    float* xw     = ws + 24587;
    float* yraw   = ws + 106507;
    float* h      = ws + 188427;
    float* slab   = ws + 270592;
    float* out    = (float*)d_out;

    // zero c0 + accum + Zcount in one shot ([0, 8203) floats)
    hipMemsetAsync(c0, 0, 8203 * sizeof(float), stream);

    kS0   <<<320,  256, 0, stream>>>(x, W1, xw);
    kMain <<<1024, 256, 0, stream>>>(adj, xw, dinv, yraw, slab, Zcount, Zlist);
    kRedC1<<<256,  256, 0, stream>>>(slab, c0);
    kRedC2<<<32,   256, 0, stream>>>(adj, dinv, c0, Zcount, Zlist);
    kFix  <<<64,   128, 0, stream>>>(adj, xw, yraw, dinv, b1, h, Zcount, Zlist);
    kF1   <<<32,   256, 0, stream>>>(h, dinv, c0, W2, accum);
    kF2   <<<1,    64,  0, stream>>>(accum, b2, fc1W, fc1b, fcW, fcb, out);
}